// Round 3
// baseline (329.613 us; speedup 1.0000x reference)
//
#include <hip/hip_runtime.h>
#include <hip/hip_bf16.h>
#include <cstdint>
#include <cstddef>

typedef __attribute__((ext_vector_type(8))) short short8;
typedef __attribute__((ext_vector_type(4))) float f32x4;
typedef __attribute__((ext_vector_type(4))) unsigned int u32x4;

#define NDIM 100
#define NSTEP 50
#define NPATH 8192
#define XSTR 128   // X row: position i holds physical dim k(i)=(i&7)*16+(i>>3); dim100=t at pos38
#define ESTR 128   // E row: same permutation; e = 0.2*S*w, zero-padded

__device__ __forceinline__ unsigned short f2b(float f){
  unsigned int u = __float_as_uint(f);
  u += 0x7fffu + ((u >> 16) & 1u);          // RNE
  return (unsigned short)(u >> 16);
}
__device__ __forceinline__ float b2f(unsigned short h){
  return __uint_as_float(((unsigned int)h) << 16);
}
__device__ __forceinline__ float gelu_fast(float y){
  // y * sigmoid(1.702 y) ; exp folded to exp2 (1.702*log2e = 2.4554673)
  float u = __builtin_amdgcn_exp2f(-2.4554673f * y);
  return y * __builtin_amdgcn_rcpf(1.f + u);
}
__device__ __forceinline__ float sigm_fast(float x){
  float u = __builtin_amdgcn_exp2f(-1.4426950f * x);
  return __builtin_amdgcn_rcpf(1.f + u);
}

// ---------------- weight prep: B-frag-ordered, K-permuted, bf16 ----------------
// WTB element idx = ((((L*8+ct)*4+ks)*16+c)*4+g)*8 + j  holds  W_L[kphys][n]
// with n = ct*16+c, k' = 32ks+8g+j, kphys = (k'&7)*16 + (k'>>3).
// One b128 load per (L,ct,ks) is 64-lane contiguous (1 KiB) and L1-resident.
__global__ __launch_bounds__(256) void prep_weights(
    const float* __restrict__ W1, const float* __restrict__ W2,
    const float* __restrict__ W3, const float* __restrict__ W4,
    unsigned short* __restrict__ WTB)
{
  int idx = blockIdx.x * 256 + threadIdx.x;   // grid covers exactly 65536
  int j  = idx & 7;
  int unit = idx >> 3;
  int g  = unit & 3;
  int c  = (unit >> 2) & 15;
  int ks = (unit >> 6) & 3;
  int ct = (unit >> 8) & 7;
  int L  = unit >> 11;
  int kp = 32 * ks + 8 * g + j;
  int k  = (kp & 7) * 16 + (kp >> 3);         // physical k
  int n  = ct * 16 + c;
  float v;
  if (L == 0)      v = (k <= NDIM) ? W1[k * 128 + n] : 0.f;
  else if (L == 1) v = W2[k * 128 + n];
  else if (L == 2) v = W3[k * 128 + n];
  else             v = (n < NDIM) ? W4[k * NDIM + n] : 0.f;
  WTB[idx] = f2b(v);
}

// ---------------- Phase A: S-chain scan -> permuted X / E rows + final S ----------------
// thread t of a path owns dims d0=(t&7)*16+(t>>3) and d1=d0+8 -> writes X/E positions t, t+64
// (contiguous per wave). d0==100 exactly at t=38 (the time input).
__global__ __launch_bounds__(256) void phaseA(
    const float* __restrict__ dw, const float* __restrict__ tg,
    unsigned short* __restrict__ X, unsigned short* __restrict__ E,
    float* __restrict__ Sout, int path0)
{
  const int pb = threadIdx.x >> 6;
  const int t  = threadIdx.x & 63;
  const int bl = blockIdx.x * 4 + pb;          // chunk-local path
  const int b  = path0 + bl;
  const int d0 = (t & 7) * 16 + (t >> 3);
  const int d1 = d0 + 8;
  float s0 = 100.f, s1 = 100.f;
  const float* dwb = dw + (long)b * NSTEP * NDIM;
  const float* tgb = tg + (long)b * NSTEP;
  unsigned short* Xb = X + (long)bl * NSTEP * XSTR;
  unsigned short* Eb = E + (long)bl * NSTEP * ESTR;
  for (int i = 0; i < NSTEP; ++i){
    float tv = tgb[i];
    float w0 = (d0 < NDIM) ? dwb[i * NDIM + d0] : 0.f;
    float w1 = (d1 < NDIM) ? dwb[i * NDIM + d1] : 0.f;
    unsigned short* Xr = Xb + i * XSTR;
    unsigned short* Er = Eb + i * ESTR;
    Xr[t]      = (d0 < NDIM) ? f2b(s0 * 0.01f) : ((d0 == NDIM) ? f2b(tv) : (unsigned short)0);
    Xr[t + 64] = (d1 < NDIM) ? f2b(s1 * 0.01f) : (unsigned short)0;   // d1 is never ==100
    Er[t]      = (d0 < NDIM) ? f2b(0.2f * s0 * w0) : (unsigned short)0;
    Er[t + 64] = (d1 < NDIM) ? f2b(0.2f * s1 * w1) : (unsigned short)0;
    s0 = fmaf(s0, 0.001f + 0.2f * w0, s0);
    s1 = fmaf(s1, 0.001f + 0.2f * w1, s1);
  }
  if (d0 < NDIM) Sout[(long)b * NDIM + d0] = s0;
  if (d1 < NDIM) Sout[(long)b * NDIM + d1] = s1;
}

// ---------------- Phase B: fused 4-layer MLP, 16 rows/wave, barrier-free ----------------
// Weights read directly from global WTB (L1-hot, all waves share the 32KB tile).
// H wave-private LDS [16 rows][256B], K-permuted, XOR slot^row swizzle:
//   write (per j): lane(g,c) row=4g+j slot c^row -> one conflict-free ds_write_b128
//   read:          lane(g,c) row=c   slot (4ks+g)^c -> conflict-free ds_read_b128
// MFMA 16x16x32 bf16: A row=lane&15, k'=(lane>>4)*8+j ; C/D col=lane&15 row=4*(lane>>4)+reg.
__global__ __launch_bounds__(256, 4) void phaseB(
    const unsigned short* __restrict__ X,
    const unsigned short* __restrict__ E,
    const unsigned short* __restrict__ WTB,
    const float* __restrict__ b1, const float* __restrict__ g1, const float* __restrict__ be1,
    const float* __restrict__ b2, const float* __restrict__ g2, const float* __restrict__ be2,
    const float* __restrict__ b3, const float* __restrict__ g3, const float* __restrict__ be3,
    const float* __restrict__ b4,
    float* __restrict__ cbuf, long row0)
{
  __shared__ __align__(16) char lds[16384];
  const int tid = threadIdx.x;
  const int w = tid >> 6;
  const int l = tid & 63;
  const int g = l >> 4;
  const int c = l & 15;
  char* const H = lds + w * 4096;
  const long waveRow = (long)blockIdx.x * 64 + w * 16;

  short8 af[4];
  // layer-1 A-frags straight from global X (positions are already permuted-k)
  {
    const unsigned short* xr = X + (waveRow + c) * XSTR;
    #pragma unroll
    for (int ks = 0; ks < 4; ++ks) af[ks] = *(const short8*)(xr + 32 * ks + 8 * g);
  }

  auto mfma_block = [&](f32x4 (&acc)[8], const unsigned short* WL, const float* bb, bool pad){
    #pragma unroll
    for (int ct = 0; ct < 8; ++ct){
      int col = ct * 16 + c;
      float bias = pad ? ((col < NDIM) ? bb[col] : 0.f) : bb[col];
      f32x4 z; z[0] = bias; z[1] = bias; z[2] = bias; z[3] = bias;
      acc[ct] = z;
      const unsigned short* wp = WL + ct * 2048 + c * 32 + g * 8;
      #pragma unroll
      for (int ks = 0; ks < 4; ++ks){
        short8 bf = *(const short8*)(wp + ks * 512);
        acc[ct] = __builtin_amdgcn_mfma_f32_16x16x32_bf16(af[ks], bf, acc[ct], 0, 0, 0);
      }
    }
  };

  auto layer_ln = [&](int L, const float* bb, const float* gg, const float* bebe){
    f32x4 acc[8];
    mfma_block(acc, WTB + L * 16384, bb, false);
    float gv[8], bev[8];
    #pragma unroll
    for (int ct = 0; ct < 8; ++ct){ gv[ct] = gg[ct * 16 + c]; bev[ct] = bebe[ct * 16 + c]; }
    #pragma unroll
    for (int j = 0; j < 4; ++j){
      float s1 = 0.f, s2 = 0.f;
      #pragma unroll
      for (int ct = 0; ct < 8; ++ct){ float x = acc[ct][j]; s1 += x; s2 = fmaf(x, x, s2); }
      s1 += __shfl_xor(s1, 1, 64); s2 += __shfl_xor(s2, 1, 64);
      s1 += __shfl_xor(s1, 2, 64); s2 += __shfl_xor(s2, 2, 64);
      s1 += __shfl_xor(s1, 4, 64); s2 += __shfl_xor(s2, 4, 64);
      s1 += __shfl_xor(s1, 8, 64); s2 += __shfl_xor(s2, 8, 64);
      float mu = s1 * 0.0078125f;
      float rstd = rsqrtf(fmaf(-mu, mu, s2 * 0.0078125f) + 1e-5f);
      int row = 4 * g + j;
      u32x4 ov;
      #pragma unroll
      for (int p = 0; p < 4; ++p){
        float h0 = gelu_fast((acc[2*p  ][j] - mu) * (rstd * gv[2*p  ]) + bev[2*p  ]);
        float h1 = gelu_fast((acc[2*p+1][j] - mu) * (rstd * gv[2*p+1]) + bev[2*p+1]);
        unsigned int pk;
        asm("v_cvt_pk_bf16_f32 %0, %1, %2" : "=v"(pk) : "v"(h0), "v"(h1));
        ov[p] = pk;
      }
      *(u32x4*)(H + row * 256 + ((c ^ row) << 4)) = ov;   // conflict-free b128
    }
    // next-layer A-frags from H
    #pragma unroll
    for (int ks = 0; ks < 4; ++ks)
      af[ks] = *(const short8*)(H + c * 256 + (((4 * ks + g) ^ c) << 4));
  };

  auto layer_out = [&](){
    f32x4 acc[8];
    mfma_block(acc, WTB + 3 * 16384, b4, true);
    #pragma unroll
    for (int j = 0; j < 4; ++j){
      long rloc = waveRow + 4 * g + j;
      short8 e8 = *(const short8*)(E + rloc * ESTR + c * 8);  // cols {ct*16+c}, ct=0..7
      float pg = 0.f;
      #pragma unroll
      for (int ct = 0; ct < 8; ++ct){
        float z = sigm_fast(acc[ct][j]);
        pg = fmaf(z, b2f((unsigned short)e8[ct]), pg);        // pad cols have e=0
      }
      pg += __shfl_xor(pg, 1, 64);
      pg += __shfl_xor(pg, 2, 64);
      pg += __shfl_xor(pg, 4, 64);
      pg += __shfl_xor(pg, 8, 64);
      if (c == 0) cbuf[row0 + rloc] = pg;
    }
  };

  layer_ln(0, b1, g1, be1);
  layer_ln(1, b2, g2, be2);
  layer_ln(2, b3, g3, be3);
  layer_out();
}

// ---------------- Phase C: affine fold -> Y ----------------
__global__ __launch_bounds__(256) void phaseC(const float* __restrict__ cbuf,
                                              const float* __restrict__ Y0,
                                              float* __restrict__ Yout)
{
  int b = blockIdx.x * 256 + threadIdx.x;
  if (b >= NPATH) return;
  const float kk = 1.0f + 0.05f * (1.0f / 50.0f);   // 1 + R*DT
  float y = Y0[0];
  const float* cb = cbuf + (long)b * NSTEP;
  #pragma unroll 10
  for (int i = 0; i < NSTEP; ++i) y = y * kk + cb[i];
  Yout[b] = y;
}

extern "C" void kernel_launch(void* const* d_in, const int* in_sizes, int n_in,
                              void* d_out, int out_size, void* d_ws, size_t ws_size,
                              hipStream_t stream)
{
  const float* dw  = (const float*)d_in[0];
  const float* tg  = (const float*)d_in[1];
  const float* W1  = (const float*)d_in[2];
  const float* b1  = (const float*)d_in[3];
  const float* g1  = (const float*)d_in[4];
  const float* be1 = (const float*)d_in[5];
  const float* W2  = (const float*)d_in[6];
  const float* b2  = (const float*)d_in[7];
  const float* g2  = (const float*)d_in[8];
  const float* be2 = (const float*)d_in[9];
  const float* W3  = (const float*)d_in[10];
  const float* b3  = (const float*)d_in[11];
  const float* g3  = (const float*)d_in[12];
  const float* be3 = (const float*)d_in[13];
  const float* W4  = (const float*)d_in[14];
  const float* b4  = (const float*)d_in[15];
  const float* Y0  = (const float*)d_in[16];
  float* out = (float*)d_out;               // [0,8192): Y ; [8192,8192+819200): S

  char* ws = (char*)d_ws;
  unsigned short* WTB = (unsigned short*)ws;        // 131072 B
  float* cbuf = (float*)(ws + 131072);              // 409600 * 4 B
  char* chunk = ws + 1769472;                       // X/E chunk region (16B aligned)

  prep_weights<<<256, 256, 0, stream>>>(W1, W2, W3, W4, WTB);

  long avail = (long)ws_size - 1769472L;
  long pc = (avail > 0) ? (avail / 25600L) : 0;     // per-path: 12800 (X) + 12800 (E) B
  if (pc > 8192) pc = 8192;
  pc -= pc % 128;                                   // rows stay multiple of 64, paths %4==0
  if (pc < 128) pc = 128;

  for (long p0 = 0; p0 < 8192; p0 += pc){
    long np = 8192 - p0; if (np > pc) np = pc;
    unsigned short* Xc = (unsigned short*)chunk;
    unsigned short* Ec = Xc + np * 50L * XSTR;
    phaseA<<<(int)(np / 4), 256, 0, stream>>>(dw, tg, Xc, Ec, out + 8192, (int)p0);
    long nrows = np * 50L;
    phaseB<<<(int)(nrows / 64), 256, 0, stream>>>(Xc, Ec, WTB,
        b1, g1, be1, b2, g2, be2, b3, g3, be3, b4, cbuf, p0 * 50L);
  }
  phaseC<<<32, 256, 0, stream>>>(cbuf, Y0, out);
}

// Round 4
// 253.796 us; speedup vs baseline: 1.2987x; 1.2987x over previous
//
#include <hip/hip_runtime.h>
#include <hip/hip_bf16.h>
#include <cstdint>
#include <cstddef>

typedef __attribute__((ext_vector_type(8))) short short8;
typedef __attribute__((ext_vector_type(4))) float f32x4;
typedef __attribute__((ext_vector_type(4))) unsigned int u32x4;

#define NDIM 100
#define NSTEP 50
#define NPATH 8192
#define XSTR 128   // X row: position i holds physical dim k(i)=(i&7)*16+(i>>3); dim100=t at pos38
#define ESTR 128   // E row: same permutation; e = 0.2*S*w, zero-padded

typedef const __attribute__((address_space(1))) unsigned int glb_u32;
typedef __attribute__((address_space(3))) unsigned int lds_u32;

__device__ __forceinline__ unsigned short f2b(float f){
  unsigned int u = __float_as_uint(f);
  u += 0x7fffu + ((u >> 16) & 1u);          // RNE
  return (unsigned short)(u >> 16);
}
__device__ __forceinline__ float b2f(unsigned short h){
  return __uint_as_float(((unsigned int)h) << 16);
}
__device__ __forceinline__ float gelu_fast(float y){
  // y * sigmoid(1.702 y) ; exp folded to exp2 (1.702*log2e = 2.4554673)
  float u = __builtin_amdgcn_exp2f(-2.4554673f * y);
  return y * __builtin_amdgcn_rcpf(1.f + u);
}
__device__ __forceinline__ float sigm_fast(float x){
  float u = __builtin_amdgcn_exp2f(-1.4426950f * x);
  return __builtin_amdgcn_rcpf(1.f + u);
}

// ---------------- weight prep: LDS-image layout, swizzle baked in ----------------
// WTS elem ((L*128 + n)*16 + s)*8 + j  =  W_L[kphys][n]
// where logical chunk lc = s ^ (n&15), kphys = j*16 + lc  (K-permutation).
// phaseB stages this LINEARLY into LDS (global_load_lds, fully coalesced);
// read at slot s=(4ks+g)^c then yields logical chunk 4ks+g for row n=ct*16+c,
// the bank-conflict-free pattern verified in R3 (full-c XOR, 16-slot spread).
__global__ __launch_bounds__(256) void prep_weights(
    const float* __restrict__ W1, const float* __restrict__ W2,
    const float* __restrict__ W3, const float* __restrict__ W4,
    unsigned short* __restrict__ WTS)
{
  int idx = blockIdx.x * 256 + threadIdx.x;   // grid covers exactly 65536
  int j = idx & 7;
  int s = (idx >> 3) & 15;
  int n = (idx >> 7) & 127;
  int L = idx >> 14;
  int lc = s ^ (n & 15);
  int k  = j * 16 + lc;                       // physical k
  float v;
  if (L == 0)      v = (k <= NDIM) ? W1[k * 128 + n] : 0.f;
  else if (L == 1) v = W2[k * 128 + n];
  else if (L == 2) v = W3[k * 128 + n];
  else             v = (n < NDIM) ? W4[k * NDIM + n] : 0.f;
  WTS[idx] = f2b(v);
}

// ---------------- Phase A: S-chain scan -> permuted X / E rows + final S ----------------
// thread t owns dims d0=(t&7)*16+(t>>3), d1=d0+8 -> writes X/E positions t, t+64.
// d0==100 exactly at t=38 (time input).
__global__ __launch_bounds__(256) void phaseA(
    const float* __restrict__ dw, const float* __restrict__ tg,
    unsigned short* __restrict__ X, unsigned short* __restrict__ E,
    float* __restrict__ Sout, int path0)
{
  const int pb = threadIdx.x >> 6;
  const int t  = threadIdx.x & 63;
  const int bl = blockIdx.x * 4 + pb;          // chunk-local path
  const int b  = path0 + bl;
  const int d0 = (t & 7) * 16 + (t >> 3);
  const int d1 = d0 + 8;
  float s0 = 100.f, s1 = 100.f;
  const float* dwb = dw + (long)b * NSTEP * NDIM;
  const float* tgb = tg + (long)b * NSTEP;
  unsigned short* Xb = X + (long)bl * NSTEP * XSTR;
  unsigned short* Eb = E + (long)bl * NSTEP * ESTR;
  for (int i = 0; i < NSTEP; ++i){
    float tv = tgb[i];
    float w0 = (d0 < NDIM) ? dwb[i * NDIM + d0] : 0.f;
    float w1 = (d1 < NDIM) ? dwb[i * NDIM + d1] : 0.f;
    unsigned short* Xr = Xb + i * XSTR;
    unsigned short* Er = Eb + i * ESTR;
    Xr[t]      = (d0 < NDIM) ? f2b(s0 * 0.01f) : ((d0 == NDIM) ? f2b(tv) : (unsigned short)0);
    Xr[t + 64] = (d1 < NDIM) ? f2b(s1 * 0.01f) : (unsigned short)0;   // d1 is never ==100
    Er[t]      = (d0 < NDIM) ? f2b(0.2f * s0 * w0) : (unsigned short)0;
    Er[t + 64] = (d1 < NDIM) ? f2b(0.2f * s1 * w1) : (unsigned short)0;
    s0 = fmaf(s0, 0.001f + 0.2f * w0, s0);
    s1 = fmaf(s1, 0.001f + 0.2f * w1, s1);
  }
  if (d0 < NDIM) Sout[(long)b * NDIM + d0] = s0;
  if (d1 < NDIM) Sout[(long)b * NDIM + d1] = s1;
}

// ---------------- Phase B: fused 4-layer MLP, 16 rows/wave ----------------
// Weights: block-shared LDS [128 rows][16 slots][16B], staged linearly from the
// pre-swizzled WTS image; read slot=(4ks+g)^c -> conflict-free b128.
// H: wave-private [16 rows][256B], slot^row swizzle, cvt_pk b128 writes (0 conflicts).
// MFMA 16x16x32 bf16: A row=lane&15 k'=(lane>>4)*8+j ; C/D col=lane&15 row=4*(lane>>4)+reg.
__global__ __launch_bounds__(256, 3) void phaseB(
    const unsigned short* __restrict__ X,
    const unsigned short* __restrict__ E,
    const unsigned short* __restrict__ WTS,
    const float* __restrict__ b1, const float* __restrict__ g1, const float* __restrict__ be1,
    const float* __restrict__ b2, const float* __restrict__ g2, const float* __restrict__ be2,
    const float* __restrict__ b3, const float* __restrict__ g3, const float* __restrict__ be3,
    const float* __restrict__ b4,
    float* __restrict__ cbuf, long row0)
{
  __shared__ __align__(16) char lds[49152];
  char* const wbuf = lds;                         // 32768 B: one layer's B-tile
  const int tid = threadIdx.x;
  const int w = tid >> 6;
  const int l = tid & 63;
  const int g = l >> 4;
  const int c = l & 15;
  char* const H = lds + 32768 + w * 4096;         // per-wave 16 rows x 256 B
  const long waveRow = (long)blockIdx.x * 64 + w * 16;

  // stage one 32 KB layer tile, fully linear (swizzle pre-baked in WTS)
  auto stage = [&](int Loff){
    #pragma unroll
    for (int it = 0; it < 8; ++it){
      int chunk = w * 8 + it;                     // 1 KiB units, 32 per block
      __builtin_amdgcn_global_load_lds((glb_u32*)(WTS + Loff + chunk * 512 + l * 8),
          (lds_u32*)(wbuf + chunk * 1024), 16, 0, 0);
    }
  };

  short8 af[4];
  // layer-1 A-frags straight from global X (positions already permuted-k)
  {
    const unsigned short* xr = X + (waveRow + c) * XSTR;
    #pragma unroll
    for (int ks = 0; ks < 4; ++ks) af[ks] = *(const short8*)(xr + 32 * ks + 8 * g);
  }

  auto mfma_block = [&](f32x4 (&acc)[8], const float* bb, bool pad){
    #pragma unroll
    for (int ct = 0; ct < 8; ++ct){
      int col = ct * 16 + c;
      float bias = pad ? ((col < NDIM) ? bb[col] : 0.f) : bb[col];
      f32x4 z; z[0] = bias; z[1] = bias; z[2] = bias; z[3] = bias;
      acc[ct] = z;
      const char* rowp = wbuf + ((ct * 16 + c) << 8);
      #pragma unroll
      for (int ks = 0; ks < 4; ++ks){
        short8 bf = *(const short8*)(rowp + (((4 * ks + g) ^ c) << 4));
        acc[ct] = __builtin_amdgcn_mfma_f32_16x16x32_bf16(af[ks], bf, acc[ct], 0, 0, 0);
      }
    }
  };

  auto layer_ln = [&](const float* bb, const float* gg, const float* bebe){
    f32x4 acc[8];
    mfma_block(acc, bb, false);
    float gv[8], bev[8];
    #pragma unroll
    for (int ct = 0; ct < 8; ++ct){ gv[ct] = gg[ct * 16 + c]; bev[ct] = bebe[ct * 16 + c]; }
    #pragma unroll
    for (int j = 0; j < 4; ++j){
      float s1 = 0.f, s2 = 0.f;
      #pragma unroll
      for (int ct = 0; ct < 8; ++ct){ float x = acc[ct][j]; s1 += x; s2 = fmaf(x, x, s2); }
      s1 += __shfl_xor(s1, 1, 64); s2 += __shfl_xor(s2, 1, 64);
      s1 += __shfl_xor(s1, 2, 64); s2 += __shfl_xor(s2, 2, 64);
      s1 += __shfl_xor(s1, 4, 64); s2 += __shfl_xor(s2, 4, 64);
      s1 += __shfl_xor(s1, 8, 64); s2 += __shfl_xor(s2, 8, 64);
      float mu = s1 * 0.0078125f;
      float rstd = rsqrtf(fmaf(-mu, mu, s2 * 0.0078125f) + 1e-5f);
      int row = 4 * g + j;
      u32x4 ov;
      #pragma unroll
      for (int p = 0; p < 4; ++p){
        float h0 = gelu_fast((acc[2*p  ][j] - mu) * (rstd * gv[2*p  ]) + bev[2*p  ]);
        float h1 = gelu_fast((acc[2*p+1][j] - mu) * (rstd * gv[2*p+1]) + bev[2*p+1]);
        unsigned int pk;
        asm("v_cvt_pk_bf16_f32 %0, %1, %2" : "=v"(pk) : "v"(h0), "v"(h1));
        ov[p] = pk;
      }
      *(u32x4*)(H + row * 256 + ((c ^ row) << 4)) = ov;   // conflict-free b128
    }
    // next-layer A-frags from H
    #pragma unroll
    for (int ks = 0; ks < 4; ++ks)
      af[ks] = *(const short8*)(H + c * 256 + (((4 * ks + g) ^ c) << 4));
  };

  auto layer_out = [&](){
    f32x4 acc[8];
    mfma_block(acc, b4, true);
    #pragma unroll
    for (int j = 0; j < 4; ++j){
      long rloc = waveRow + 4 * g + j;
      short8 e8 = *(const short8*)(E + rloc * ESTR + c * 8);  // cols {ct*16+c}
      float pg = 0.f;
      #pragma unroll
      for (int ct = 0; ct < 8; ++ct){
        float z = sigm_fast(acc[ct][j]);
        pg = fmaf(z, b2f((unsigned short)e8[ct]), pg);        // pad cols have e=0
      }
      pg += __shfl_xor(pg, 1, 64);
      pg += __shfl_xor(pg, 2, 64);
      pg += __shfl_xor(pg, 4, 64);
      pg += __shfl_xor(pg, 8, 64);
      if (c == 0) cbuf[row0 + rloc] = pg;
    }
  };

  stage(0);
  __syncthreads();
  layer_ln(b1, g1, be1);
  __syncthreads();  stage(16384);  __syncthreads();
  layer_ln(b2, g2, be2);
  __syncthreads();  stage(32768);  __syncthreads();
  layer_ln(b3, g3, be3);
  __syncthreads();  stage(49152);  __syncthreads();
  layer_out();
}

// ---------------- Phase C: affine fold -> Y ----------------
__global__ __launch_bounds__(256) void phaseC(const float* __restrict__ cbuf,
                                              const float* __restrict__ Y0,
                                              float* __restrict__ Yout)
{
  int b = blockIdx.x * 256 + threadIdx.x;
  if (b >= NPATH) return;
  const float kk = 1.0f + 0.05f * (1.0f / 50.0f);   // 1 + R*DT
  float y = Y0[0];
  const float* cb = cbuf + (long)b * NSTEP;
  #pragma unroll 10
  for (int i = 0; i < NSTEP; ++i) y = y * kk + cb[i];
  Yout[b] = y;
}

extern "C" void kernel_launch(void* const* d_in, const int* in_sizes, int n_in,
                              void* d_out, int out_size, void* d_ws, size_t ws_size,
                              hipStream_t stream)
{
  const float* dw  = (const float*)d_in[0];
  const float* tg  = (const float*)d_in[1];
  const float* W1  = (const float*)d_in[2];
  const float* b1  = (const float*)d_in[3];
  const float* g1  = (const float*)d_in[4];
  const float* be1 = (const float*)d_in[5];
  const float* W2  = (const float*)d_in[6];
  const float* b2  = (const float*)d_in[7];
  const float* g2  = (const float*)d_in[8];
  const float* be2 = (const float*)d_in[9];
  const float* W3  = (const float*)d_in[10];
  const float* b3  = (const float*)d_in[11];
  const float* g3  = (const float*)d_in[12];
  const float* be3 = (const float*)d_in[13];
  const float* W4  = (const float*)d_in[14];
  const float* b4  = (const float*)d_in[15];
  const float* Y0  = (const float*)d_in[16];
  float* out = (float*)d_out;               // [0,8192): Y ; [8192,8192+819200): S

  char* ws = (char*)d_ws;
  unsigned short* WTS = (unsigned short*)ws;        // 131072 B
  float* cbuf = (float*)(ws + 131072);              // 409600 * 4 B
  char* chunk = ws + 1769472;                       // X/E chunk region (16B aligned)

  prep_weights<<<256, 256, 0, stream>>>(W1, W2, W3, W4, WTS);

  long avail = (long)ws_size - 1769472L;
  long pc = (avail > 0) ? (avail / 25600L) : 0;     // per-path: 12800 (X) + 12800 (E) B
  if (pc > 8192) pc = 8192;
  pc -= pc % 128;                                   // rows multiple of 64, paths %4==0
  if (pc < 128) pc = 128;

  for (long p0 = 0; p0 < 8192; p0 += pc){
    long np = 8192 - p0; if (np > pc) np = pc;
    unsigned short* Xc = (unsigned short*)chunk;
    unsigned short* Ec = Xc + np * 50L * XSTR;
    phaseA<<<(int)(np / 4), 256, 0, stream>>>(dw, tg, Xc, Ec, out + 8192, (int)p0);
    long nrows = np * 50L;
    phaseB<<<(int)(nrows / 64), 256, 0, stream>>>(Xc, Ec, WTS,
        b1, g1, be1, b2, g2, be2, b3, g3, be3, b4, cbuf, p0 * 50L);
  }
  phaseC<<<32, 256, 0, stream>>>(cbuf, Y0, out);
}

// Round 5
// 237.868 us; speedup vs baseline: 1.3857x; 1.0670x over previous
//
#include <hip/hip_runtime.h>
#include <hip/hip_bf16.h>
#include <cstdint>
#include <cstddef>

typedef __attribute__((ext_vector_type(8))) short short8;
typedef __attribute__((ext_vector_type(4))) float f32x4;
typedef __attribute__((ext_vector_type(4))) unsigned int u32x4;

#define NDIM 100
#define NSTEP 50
#define NPATH 8192
#define XSTR 128   // X row: position i holds physical dim k(i)=(i&7)*16+(i>>3); dim100=t at pos38
#define ESTR 128   // E row: same permutation; e = 0.2*S*w, zero-padded

typedef const __attribute__((address_space(1))) unsigned int glb_u32;
typedef __attribute__((address_space(3))) unsigned int lds_u32;

__device__ __forceinline__ unsigned short f2b(float f){
  unsigned int u = __float_as_uint(f);
  u += 0x7fffu + ((u >> 16) & 1u);          // RNE
  return (unsigned short)(u >> 16);
}
__device__ __forceinline__ float b2f(unsigned short h){
  return __uint_as_float(((unsigned int)h) << 16);
}
__device__ __forceinline__ float gelu_fast(float y){
  // y * sigmoid(1.702 y) ; exp folded to exp2 (1.702*log2e = 2.4554673)
  float u = __builtin_amdgcn_exp2f(-2.4554673f * y);
  return y * __builtin_amdgcn_rcpf(1.f + u);
}
__device__ __forceinline__ float sigm_fast(float x){
  float u = __builtin_amdgcn_exp2f(-1.4426950f * x);
  return __builtin_amdgcn_rcpf(1.f + u);
}

// ---------------- weight prep: LDS-image layout, swizzle baked in ----------------
// WTS elem ((L*128 + n)*16 + s)*8 + j  =  W_L[kphys][n]
// where logical chunk lc = s ^ (n&15), kphys = j*16 + lc  (K-permutation).
// phaseB stages this LINEARLY into LDS; read slot s=(4ks+g)^c -> conflict-free b128.
__global__ __launch_bounds__(256) void prep_weights(
    const float* __restrict__ W1, const float* __restrict__ W2,
    const float* __restrict__ W3, const float* __restrict__ W4,
    unsigned short* __restrict__ WTS)
{
  int idx = blockIdx.x * 256 + threadIdx.x;   // grid covers exactly 65536
  int j = idx & 7;
  int s = (idx >> 3) & 15;
  int n = (idx >> 7) & 127;
  int L = idx >> 14;
  int lc = s ^ (n & 15);
  int k  = j * 16 + lc;                       // physical k
  float v;
  if (L == 0)      v = (k <= NDIM) ? W1[k * 128 + n] : 0.f;
  else if (L == 1) v = W2[k * 128 + n];
  else if (L == 2) v = W3[k * 128 + n];
  else             v = (n < NDIM) ? W4[k * NDIM + n] : 0.f;
  WTS[idx] = f2b(v);
}

// ---------------- param prep: PPAR[L][p][c][ct] f32 (p: 0=bias 1=gamma 2=beta) ----------------
// lane c reads each param vector as two float4s (ct 0..3, 4..7). L=3 only p=0 (b4, padded).
__global__ __launch_bounds__(256) void prep_params(
    const float* __restrict__ b1, const float* __restrict__ g1, const float* __restrict__ be1,
    const float* __restrict__ b2, const float* __restrict__ g2, const float* __restrict__ be2,
    const float* __restrict__ b3, const float* __restrict__ g3, const float* __restrict__ be3,
    const float* __restrict__ b4, float* __restrict__ PPAR)
{
  int idx = blockIdx.x * 256 + threadIdx.x;   // grid covers 1536
  if (idx >= 1536) return;
  int ct = idx & 7;
  int c  = (idx >> 3) & 15;
  int p  = (idx >> 7) % 3;
  int L  = idx / 384;
  int col = ct * 16 + c;
  const float* v;
  if (L == 0)      v = (p == 0) ? b1 : (p == 1) ? g1 : be1;
  else if (L == 1) v = (p == 0) ? b2 : (p == 1) ? g2 : be2;
  else if (L == 2) v = (p == 0) ? b3 : (p == 1) ? g3 : be3;
  else             v = b4;
  float val;
  if (L == 3) val = (p == 0 && col < NDIM) ? b4[col] : 0.f;
  else        val = v[col];
  PPAR[idx] = val;
}

// ---------------- Phase A: S-chain scan -> permuted X / E rows + final S ----------------
__global__ __launch_bounds__(256) void phaseA(
    const float* __restrict__ dw, const float* __restrict__ tg,
    unsigned short* __restrict__ X, unsigned short* __restrict__ E,
    float* __restrict__ Sout, int path0)
{
  const int pb = threadIdx.x >> 6;
  const int t  = threadIdx.x & 63;
  const int bl = blockIdx.x * 4 + pb;          // chunk-local path
  const int b  = path0 + bl;
  const int d0 = (t & 7) * 16 + (t >> 3);
  const int d1 = d0 + 8;
  float s0 = 100.f, s1 = 100.f;
  const float* dwb = dw + (long)b * NSTEP * NDIM;
  const float* tgb = tg + (long)b * NSTEP;
  unsigned short* Xb = X + (long)bl * NSTEP * XSTR;
  unsigned short* Eb = E + (long)bl * NSTEP * ESTR;
  for (int i = 0; i < NSTEP; ++i){
    float tv = tgb[i];
    float w0 = (d0 < NDIM) ? dwb[i * NDIM + d0] : 0.f;
    float w1 = (d1 < NDIM) ? dwb[i * NDIM + d1] : 0.f;
    unsigned short* Xr = Xb + i * XSTR;
    unsigned short* Er = Eb + i * ESTR;
    Xr[t]      = (d0 < NDIM) ? f2b(s0 * 0.01f) : ((d0 == NDIM) ? f2b(tv) : (unsigned short)0);
    Xr[t + 64] = (d1 < NDIM) ? f2b(s1 * 0.01f) : (unsigned short)0;   // d1 is never ==100
    Er[t]      = (d0 < NDIM) ? f2b(0.2f * s0 * w0) : (unsigned short)0;
    Er[t + 64] = (d1 < NDIM) ? f2b(0.2f * s1 * w1) : (unsigned short)0;
    s0 = fmaf(s0, 0.001f + 0.2f * w0, s0);
    s1 = fmaf(s1, 0.001f + 0.2f * w1, s1);
  }
  if (d0 < NDIM) Sout[(long)b * NDIM + d0] = s0;
  if (d1 < NDIM) Sout[(long)b * NDIM + d1] = s1;
}

// ---------------- Phase B: fused 4-layer MLP, 2 row-tiles/wave (128 rows/block) ----------------
// Weights: block-shared LDS [128][16 slots][16B], staged linearly from pre-swizzled WTS;
// read slot=(4ks+g)^c -> conflict-free b128; each read feeds BOTH tiles' MFMAs.
// H: one wave-private [16][256B] buffer, reused by tile0 then tile1 (wave-internal DS order).
// MFMA 16x16x32 bf16: A row=lane&15 k'=(lane>>4)*8+j ; C/D col=lane&15 row=4*(lane>>4)+reg.
__global__ __launch_bounds__(256, 3) void phaseB(
    const unsigned short* __restrict__ X,
    const unsigned short* __restrict__ E,
    const unsigned short* __restrict__ WTS,
    const float* __restrict__ PPAR,
    float* __restrict__ cbuf, long row0)
{
  __shared__ __align__(16) char lds[49152];
  char* const wbuf = lds;                         // 32768 B: one layer's B-tile
  const int tid = threadIdx.x;
  const int w = tid >> 6;
  const int l = tid & 63;
  const int g = l >> 4;
  const int c = l & 15;
  char* const H = lds + 32768 + w * 4096;         // per-wave 16 rows x 256 B (reused per tile)
  const long base = (long)blockIdx.x * 128 + w * 16;   // tile tt rows: base + 64*tt

  auto stage = [&](int Loff){
    #pragma unroll
    for (int it = 0; it < 8; ++it){
      int chunk = w * 8 + it;                     // 1 KiB units, 32 per block
      __builtin_amdgcn_global_load_lds((glb_u32*)(WTS + Loff + chunk * 512 + l * 8),
          (lds_u32*)(wbuf + chunk * 1024), 16, 0, 0);
    }
  };

  short8 af0[4], af1[4];
  {
    const unsigned short* xr0 = X + (base + c) * XSTR;
    const unsigned short* xr1 = X + (base + 64 + c) * XSTR;
    #pragma unroll
    for (int ks = 0; ks < 4; ++ks){
      af0[ks] = *(const short8*)(xr0 + 32 * ks + 8 * g);
      af1[ks] = *(const short8*)(xr1 + 32 * ks + 8 * g);
    }
  }

  // dual-tile MFMA block: weights read once, used twice
  auto mfma2 = [&](f32x4 (&acc0)[8], f32x4 (&acc1)[8], const f32x4 bias[2]){
    #pragma unroll
    for (int ct = 0; ct < 8; ++ct){
      float bs = ((const float*)bias)[ct];
      f32x4 z; z[0] = bs; z[1] = bs; z[2] = bs; z[3] = bs;
      acc0[ct] = z; acc1[ct] = z;
      const char* rowp = wbuf + ((ct * 16 + c) << 8);
      #pragma unroll
      for (int ks = 0; ks < 4; ++ks){
        short8 bf = *(const short8*)(rowp + (((4 * ks + g) ^ c) << 4));
        acc0[ct] = __builtin_amdgcn_mfma_f32_16x16x32_bf16(af0[ks], bf, acc0[ct], 0, 0, 0);
        acc1[ct] = __builtin_amdgcn_mfma_f32_16x16x32_bf16(af1[ks], bf, acc1[ct], 0, 0, 0);
      }
    }
  };

  // LN + GELU postproc for one tile: acc -> H -> af
  auto postproc = [&](f32x4 (&acc)[8], short8 (&af)[4],
                      const f32x4 gvv[2], const f32x4 bevv[2]){
    const float* gv = (const float*)gvv;
    const float* bev = (const float*)bevv;
    #pragma unroll
    for (int j = 0; j < 4; ++j){
      float s1 = 0.f, s2 = 0.f;
      #pragma unroll
      for (int ct = 0; ct < 8; ++ct){ float x = acc[ct][j]; s1 += x; s2 = fmaf(x, x, s2); }
      s1 += __shfl_xor(s1, 1, 64); s2 += __shfl_xor(s2, 1, 64);
      s1 += __shfl_xor(s1, 2, 64); s2 += __shfl_xor(s2, 2, 64);
      s1 += __shfl_xor(s1, 4, 64); s2 += __shfl_xor(s2, 4, 64);
      s1 += __shfl_xor(s1, 8, 64); s2 += __shfl_xor(s2, 8, 64);
      float mu = s1 * 0.0078125f;
      float rstd = rsqrtf(fmaf(-mu, mu, s2 * 0.0078125f) + 1e-5f);
      int row = 4 * g + j;
      u32x4 ov;
      #pragma unroll
      for (int p = 0; p < 4; ++p){
        float A0 = rstd * gv[2*p], A1 = rstd * gv[2*p+1];
        float C0 = fmaf(-mu, A0, bev[2*p]), C1 = fmaf(-mu, A1, bev[2*p+1]);
        float h0 = gelu_fast(fmaf(acc[2*p  ][j], A0, C0));
        float h1 = gelu_fast(fmaf(acc[2*p+1][j], A1, C1));
        unsigned int pk;
        asm("v_cvt_pk_bf16_f32 %0, %1, %2" : "=v"(pk) : "v"(h0), "v"(h1));
        ov[p] = pk;
      }
      *(u32x4*)(H + row * 256 + ((c ^ row) << 4)) = ov;   // conflict-free b128
    }
    #pragma unroll
    for (int ks = 0; ks < 4; ++ks)
      af[ks] = *(const short8*)(H + c * 256 + (((4 * ks + g) ^ c) << 4));
  };

  auto layer_ln = [&](int L){
    const f32x4* pp = (const f32x4*)(PPAR + L * 384 + c * 8);
    f32x4 bias[2], gvv[2], bevv[2];
    bias[0] = pp[0];  bias[1] = pp[1];          // [p=0][c][ct0..7]
    gvv[0]  = pp[32]; gvv[1]  = pp[33];         // p=1 at +128 floats
    bevv[0] = pp[64]; bevv[1] = pp[65];         // p=2 at +256 floats
    f32x4 acc0[8], acc1[8];
    mfma2(acc0, acc1, bias);
    postproc(acc0, af0, gvv, bevv);
    postproc(acc1, af1, gvv, bevv);
  };

  auto layer_out = [&](){
    const f32x4* pp = (const f32x4*)(PPAR + 3 * 384 + c * 8);
    f32x4 bias[2]; bias[0] = pp[0]; bias[1] = pp[1];
    f32x4 acc0[8], acc1[8];
    mfma2(acc0, acc1, bias);
    #pragma unroll
    for (int tt = 0; tt < 2; ++tt){
      f32x4* acc = tt ? acc1 : acc0;
      #pragma unroll
      for (int j = 0; j < 4; ++j){
        long rloc = base + 64 * tt + 4 * g + j;
        short8 e8 = *(const short8*)(E + rloc * ESTR + c * 8);  // cols {ct*16+c}
        float pg = 0.f;
        #pragma unroll
        for (int ct = 0; ct < 8; ++ct){
          float z = sigm_fast(acc[ct][j]);
          pg = fmaf(z, b2f((unsigned short)e8[ct]), pg);        // pad cols have e=0
        }
        pg += __shfl_xor(pg, 1, 64);
        pg += __shfl_xor(pg, 2, 64);
        pg += __shfl_xor(pg, 4, 64);
        pg += __shfl_xor(pg, 8, 64);
        if (c == 0) cbuf[row0 + rloc] = pg;
      }
    }
  };

  stage(0);
  __syncthreads();
  layer_ln(0);
  __syncthreads();  stage(16384);  __syncthreads();
  layer_ln(1);
  __syncthreads();  stage(32768);  __syncthreads();
  layer_ln(2);
  __syncthreads();  stage(49152);  __syncthreads();
  layer_out();
}

// ---------------- Phase C: affine fold -> Y ----------------
__global__ __launch_bounds__(256) void phaseC(const float* __restrict__ cbuf,
                                              const float* __restrict__ Y0,
                                              float* __restrict__ Yout)
{
  int b = blockIdx.x * 256 + threadIdx.x;
  if (b >= NPATH) return;
  const float kk = 1.0f + 0.05f * (1.0f / 50.0f);   // 1 + R*DT
  float y = Y0[0];
  const float* cb = cbuf + (long)b * NSTEP;
  #pragma unroll 10
  for (int i = 0; i < NSTEP; ++i) y = y * kk + cb[i];
  Yout[b] = y;
}

extern "C" void kernel_launch(void* const* d_in, const int* in_sizes, int n_in,
                              void* d_out, int out_size, void* d_ws, size_t ws_size,
                              hipStream_t stream)
{
  const float* dw  = (const float*)d_in[0];
  const float* tg  = (const float*)d_in[1];
  const float* W1  = (const float*)d_in[2];
  const float* b1  = (const float*)d_in[3];
  const float* g1  = (const float*)d_in[4];
  const float* be1 = (const float*)d_in[5];
  const float* W2  = (const float*)d_in[6];
  const float* b2  = (const float*)d_in[7];
  const float* g2  = (const float*)d_in[8];
  const float* be2 = (const float*)d_in[9];
  const float* W3  = (const float*)d_in[10];
  const float* b3  = (const float*)d_in[11];
  const float* g3  = (const float*)d_in[12];
  const float* be3 = (const float*)d_in[13];
  const float* W4  = (const float*)d_in[14];
  const float* b4  = (const float*)d_in[15];
  const float* Y0  = (const float*)d_in[16];
  float* out = (float*)d_out;               // [0,8192): Y ; [8192,8192+819200): S

  char* ws = (char*)d_ws;
  unsigned short* WTS = (unsigned short*)ws;        // 131072 B
  float* PPAR = (float*)(ws + 131072);              // 1536 * 4 B
  float* cbuf = (float*)(ws + 137344);              // 409600 * 4 B
  char* chunk = ws + 1775744;                       // X/E chunk region (16B aligned)

  prep_weights<<<256, 256, 0, stream>>>(W1, W2, W3, W4, WTS);
  prep_params<<<6, 256, 0, stream>>>(b1, g1, be1, b2, g2, be2, b3, g3, be3, b4, PPAR);

  long avail = (long)ws_size - 1775744L;
  long pc = (avail > 0) ? (avail / 25600L) : 0;     // per-path: 12800 (X) + 12800 (E) B
  if (pc > 8192) pc = 8192;
  pc -= pc % 128;                                   // rows multiple of 128 (6400/chunk-step)
  if (pc < 128) pc = 128;

  for (long p0 = 0; p0 < 8192; p0 += pc){
    long np = 8192 - p0; if (np > pc) np = pc;
    unsigned short* Xc = (unsigned short*)chunk;
    unsigned short* Ec = Xc + np * 50L * XSTR;
    phaseA<<<(int)(np / 4), 256, 0, stream>>>(dw, tg, Xc, Ec, out + 8192, (int)p0);
    long nrows = np * 50L;
    phaseB<<<(int)(nrows / 128), 256, 0, stream>>>(Xc, Ec, WTS, PPAR, cbuf, p0 * 50L);
  }
  phaseC<<<32, 256, 0, stream>>>(cbuf, Y0, out);
}

// Round 6
// 215.493 us; speedup vs baseline: 1.5296x; 1.1038x over previous
//
#include <hip/hip_runtime.h>
#include <hip/hip_bf16.h>
#include <cstdint>
#include <cstddef>

typedef __attribute__((ext_vector_type(8))) short short8;
typedef __attribute__((ext_vector_type(4))) float f32x4;
typedef __attribute__((ext_vector_type(4))) unsigned int u32x4;

#define NDIM 100
#define NSTEP 50
#define NPATH 8192
#define XSTR 128   // X row: position i holds physical dim k(i)=(i&7)*16+(i>>3); dim100=t at pos38
#define ESTR 128   // E row: same permutation; e = 0.2*S*w, zero-padded

typedef const __attribute__((address_space(1))) unsigned int glb_u32;
typedef __attribute__((address_space(3))) unsigned int lds_u32;

__device__ __forceinline__ unsigned short f2b(float f){
  unsigned int u = __float_as_uint(f);
  u += 0x7fffu + ((u >> 16) & 1u);          // RNE
  return (unsigned short)(u >> 16);
}
__device__ __forceinline__ float b2f(unsigned short h){
  return __uint_as_float(((unsigned int)h) << 16);
}
__device__ __forceinline__ float gelu_fast(float y){
  // y * sigmoid(1.702 y) ; exp folded to exp2 (1.702*log2e = 2.4554673)
  float u = __builtin_amdgcn_exp2f(-2.4554673f * y);
  return y * __builtin_amdgcn_rcpf(1.f + u);
}
__device__ __forceinline__ float sigm_fast(float x){
  float u = __builtin_amdgcn_exp2f(-1.4426950f * x);
  return __builtin_amdgcn_rcpf(1.f + u);
}

// ---------------- weight prep: LDS-image layout, swizzle baked in ----------------
// WTS elem ((L*128 + n)*16 + s)*8 + j  =  W_L[kphys][n]
// where logical chunk lc = s ^ (n&15), kphys = j*16 + lc  (K-permutation).
// phaseB stages this LINEARLY into LDS; read slot s=(4ks+g)^c -> conflict-free b128.
__global__ __launch_bounds__(256) void prep_weights(
    const float* __restrict__ W1, const float* __restrict__ W2,
    const float* __restrict__ W3, const float* __restrict__ W4,
    unsigned short* __restrict__ WTS)
{
  int idx = blockIdx.x * 256 + threadIdx.x;   // grid covers exactly 65536
  int j = idx & 7;
  int s = (idx >> 3) & 15;
  int n = (idx >> 7) & 127;
  int L = idx >> 14;
  int lc = s ^ (n & 15);
  int k  = j * 16 + lc;                       // physical k
  float v;
  if (L == 0)      v = (k <= NDIM) ? W1[k * 128 + n] : 0.f;
  else if (L == 1) v = W2[k * 128 + n];
  else if (L == 2) v = W3[k * 128 + n];
  else             v = (n < NDIM) ? W4[k * NDIM + n] : 0.f;
  WTS[idx] = f2b(v);
}

// ---------------- param prep: PPAR[L][p][c][ct] f32 (p: 0=bias 1=gamma 2=beta) ----------------
__global__ __launch_bounds__(256) void prep_params(
    const float* __restrict__ b1, const float* __restrict__ g1, const float* __restrict__ be1,
    const float* __restrict__ b2, const float* __restrict__ g2, const float* __restrict__ be2,
    const float* __restrict__ b3, const float* __restrict__ g3, const float* __restrict__ be3,
    const float* __restrict__ b4, float* __restrict__ PPAR)
{
  int idx = blockIdx.x * 256 + threadIdx.x;   // grid covers 1536
  if (idx >= 1536) return;
  int ct = idx & 7;
  int c  = (idx >> 3) & 15;
  int p  = (idx >> 7) % 3;
  int L  = idx / 384;
  int col = ct * 16 + c;
  const float* v;
  if (L == 0)      v = (p == 0) ? b1 : (p == 1) ? g1 : be1;
  else if (L == 1) v = (p == 0) ? b2 : (p == 1) ? g2 : be2;
  else if (L == 2) v = (p == 0) ? b3 : (p == 1) ? g3 : be3;
  else             v = b4;
  float val;
  if (L == 3) val = (p == 0 && col < NDIM) ? b4[col] : 0.f;
  else        val = v[col];
  PPAR[idx] = val;
}

// ---------------- Phase A: S-chain scan -> permuted X / E rows + final S ----------------
__global__ __launch_bounds__(256) void phaseA(
    const float* __restrict__ dw, const float* __restrict__ tg,
    unsigned short* __restrict__ X, unsigned short* __restrict__ E,
    float* __restrict__ Sout, int path0)
{
  const int pb = threadIdx.x >> 6;
  const int t  = threadIdx.x & 63;
  const int bl = blockIdx.x * 4 + pb;          // chunk-local path
  const int b  = path0 + bl;
  const int d0 = (t & 7) * 16 + (t >> 3);
  const int d1 = d0 + 8;
  float s0 = 100.f, s1 = 100.f;
  const float* dwb = dw + (long)b * NSTEP * NDIM;
  const float* tgb = tg + (long)b * NSTEP;
  unsigned short* Xb = X + (long)bl * NSTEP * XSTR;
  unsigned short* Eb = E + (long)bl * NSTEP * ESTR;
  for (int i = 0; i < NSTEP; ++i){
    float tv = tgb[i];
    float w0 = (d0 < NDIM) ? dwb[i * NDIM + d0] : 0.f;
    float w1 = (d1 < NDIM) ? dwb[i * NDIM + d1] : 0.f;
    unsigned short* Xr = Xb + i * XSTR;
    unsigned short* Er = Eb + i * ESTR;
    Xr[t]      = (d0 < NDIM) ? f2b(s0 * 0.01f) : ((d0 == NDIM) ? f2b(tv) : (unsigned short)0);
    Xr[t + 64] = (d1 < NDIM) ? f2b(s1 * 0.01f) : (unsigned short)0;   // d1 is never ==100
    Er[t]      = (d0 < NDIM) ? f2b(0.2f * s0 * w0) : (unsigned short)0;
    Er[t + 64] = (d1 < NDIM) ? f2b(0.2f * s1 * w1) : (unsigned short)0;
    s0 = fmaf(s0, 0.001f + 0.2f * w0, s0);
    s1 = fmaf(s1, 0.001f + 0.2f * w1, s1);
  }
  if (d0 < NDIM) Sout[(long)b * NDIM + d0] = s0;
  if (d1 < NDIM) Sout[(long)b * NDIM + d1] = s1;
}

// ---------------- Phase B: fused 4-layer MLP, 2 row-tiles/wave (128 rows/block) ----------------
// Weights: block-shared LDS [128][16 slots][16B], staged linearly from pre-swizzled WTS;
// read slot=(4ks+g)^c -> conflict-free b128; each read feeds BOTH tiles' MFMAs.
// Stage for layer L+1 issued right after the post-mfma barrier, DMA overlaps postproc VALU.
// All params passed BY VALUE (f32x4) — no local arrays through pointers (scratch-free).
__global__ __launch_bounds__(256, 3) void phaseB(
    const unsigned short* __restrict__ X,
    const unsigned short* __restrict__ E,
    const unsigned short* __restrict__ WTS,
    const float* __restrict__ PPAR,
    float* __restrict__ cbuf, long row0)
{
  __shared__ __align__(16) char lds[49152];
  char* const wbuf = lds;                         // 32768 B: one layer's B-tile
  const int tid = threadIdx.x;
  const int w = tid >> 6;
  const int l = tid & 63;
  const int g = l >> 4;
  const int c = l & 15;
  char* const H = lds + 32768 + w * 4096;         // per-wave 16 rows x 256 B (reused per tile)
  const long base = (long)blockIdx.x * 128 + w * 16;   // tile tt rows: base + 64*tt

  auto stage = [&](int Loff){
    #pragma unroll
    for (int it = 0; it < 8; ++it){
      int chunk = w * 8 + it;                     // 1 KiB units, 32 per block
      __builtin_amdgcn_global_load_lds((glb_u32*)(WTS + Loff + chunk * 512 + l * 8),
          (lds_u32*)(wbuf + chunk * 1024), 16, 0, 0);
    }
  };

  short8 af0[4], af1[4];
  {
    const unsigned short* xr0 = X + (base + c) * XSTR;
    const unsigned short* xr1 = X + (base + 64 + c) * XSTR;
    #pragma unroll
    for (int ks = 0; ks < 4; ++ks){
      af0[ks] = *(const short8*)(xr0 + 32 * ks + 8 * g);
      af1[ks] = *(const short8*)(xr1 + 32 * ks + 8 * g);
    }
  }

  // dual-tile MFMA block: weights read once, used twice
  auto mfma2 = [&](f32x4 (&acc0)[8], f32x4 (&acc1)[8], f32x4 blo, f32x4 bhi){
    #pragma unroll
    for (int ct = 0; ct < 8; ++ct){
      float bs = (ct < 4) ? blo[ct] : bhi[ct - 4];
      f32x4 z; z[0] = bs; z[1] = bs; z[2] = bs; z[3] = bs;
      acc0[ct] = z; acc1[ct] = z;
      const char* rowp = wbuf + ((ct * 16 + c) << 8);
      #pragma unroll
      for (int ks = 0; ks < 4; ++ks){
        short8 bf = *(const short8*)(rowp + (((4 * ks + g) ^ c) << 4));
        acc0[ct] = __builtin_amdgcn_mfma_f32_16x16x32_bf16(af0[ks], bf, acc0[ct], 0, 0, 0);
        acc1[ct] = __builtin_amdgcn_mfma_f32_16x16x32_bf16(af1[ks], bf, acc1[ct], 0, 0, 0);
      }
    }
  };

  // LN + GELU postproc for one tile: acc -> H -> af
  auto postproc = [&](f32x4 (&acc)[8], short8 (&af)[4],
                      f32x4 glo, f32x4 ghi, f32x4 belo, f32x4 behi){
    #pragma unroll
    for (int j = 0; j < 4; ++j){
      float s1 = 0.f, s2 = 0.f;
      #pragma unroll
      for (int ct = 0; ct < 8; ++ct){ float x = acc[ct][j]; s1 += x; s2 = fmaf(x, x, s2); }
      s1 += __shfl_xor(s1, 1, 64); s2 += __shfl_xor(s2, 1, 64);
      s1 += __shfl_xor(s1, 2, 64); s2 += __shfl_xor(s2, 2, 64);
      s1 += __shfl_xor(s1, 4, 64); s2 += __shfl_xor(s2, 4, 64);
      s1 += __shfl_xor(s1, 8, 64); s2 += __shfl_xor(s2, 8, 64);
      float mu = s1 * 0.0078125f;
      float rstd = rsqrtf(fmaf(-mu, mu, s2 * 0.0078125f) + 1e-5f);
      int row = 4 * g + j;
      u32x4 ov;
      #pragma unroll
      for (int p = 0; p < 4; ++p){
        float ga  = (p < 2) ? glo[2*p]     : ghi[2*p - 4];
        float gb  = (p < 2) ? glo[2*p + 1] : ghi[2*p - 3];
        float ba  = (p < 2) ? belo[2*p]     : behi[2*p - 4];
        float bb2 = (p < 2) ? belo[2*p + 1] : behi[2*p - 3];
        float A0 = rstd * ga, A1 = rstd * gb;
        float C0 = fmaf(-mu, A0, ba), C1 = fmaf(-mu, A1, bb2);
        float h0 = gelu_fast(fmaf(acc[2*p    ][j], A0, C0));
        float h1 = gelu_fast(fmaf(acc[2*p + 1][j], A1, C1));
        unsigned int pk;
        asm("v_cvt_pk_bf16_f32 %0, %1, %2" : "=v"(pk) : "v"(h0), "v"(h1));
        ov[p] = pk;
      }
      *(u32x4*)(H + row * 256 + ((c ^ row) << 4)) = ov;   // conflict-free b128
    }
    #pragma unroll
    for (int ks = 0; ks < 4; ++ks)
      af[ks] = *(const short8*)(H + c * 256 + (((4 * ks + g) ^ c) << 4));
  };

  // L4 epilogue for one tile (E rows preloaded in regs)
  auto epilogue = [&](f32x4 (&acc)[8], short8 (&ep)[4], long rbase){
    #pragma unroll
    for (int j = 0; j < 4; ++j){
      float pg = 0.f;
      #pragma unroll
      for (int ct = 0; ct < 8; ++ct){
        float z = sigm_fast(acc[ct][j]);
        pg = fmaf(z, b2f((unsigned short)ep[j][ct]), pg);   // pad cols have e=0
      }
      pg += __shfl_xor(pg, 1, 64);
      pg += __shfl_xor(pg, 2, 64);
      pg += __shfl_xor(pg, 4, 64);
      pg += __shfl_xor(pg, 8, 64);
      if (c == 0) cbuf[row0 + rbase + 4 * g + j] = pg;
    }
  };

  stage(0);
  __syncthreads();

  #pragma unroll
  for (int L = 0; L < 3; ++L){
    const float* pp = PPAR + L * 384 + c * 8;
    f32x4 blo  = *(const f32x4*)pp,         bhi  = *(const f32x4*)(pp + 4);
    f32x4 glo  = *(const f32x4*)(pp + 128), ghi  = *(const f32x4*)(pp + 132);
    f32x4 belo = *(const f32x4*)(pp + 256), behi = *(const f32x4*)(pp + 260);
    f32x4 acc0[8], acc1[8];
    mfma2(acc0, acc1, blo, bhi);
    __syncthreads();                       // all waves done reading wbuf
    stage((L + 1) * 16384);                // async DMA next layer, overlaps postproc
    postproc(acc0, af0, glo, ghi, belo, behi);
    postproc(acc1, af1, glo, ghi, belo, behi);
    __syncthreads();                       // drains vmcnt -> wbuf ready
  }

  {
    const float* pp = PPAR + 3 * 384 + c * 8;
    f32x4 blo = *(const f32x4*)pp, bhi = *(const f32x4*)(pp + 4);
    short8 ep0[4], ep1[4];
    #pragma unroll
    for (int j = 0; j < 4; ++j){
      ep0[j] = *(const short8*)(E + (base + 4 * g + j) * ESTR + c * 8);
      ep1[j] = *(const short8*)(E + (base + 64 + 4 * g + j) * ESTR + c * 8);
    }
    f32x4 acc0[8], acc1[8];
    mfma2(acc0, acc1, blo, bhi);
    epilogue(acc0, ep0, base);
    epilogue(acc1, ep1, base + 64);
  }
}

// ---------------- Phase C: affine fold -> Y ----------------
__global__ __launch_bounds__(256) void phaseC(const float* __restrict__ cbuf,
                                              const float* __restrict__ Y0,
                                              float* __restrict__ Yout)
{
  int b = blockIdx.x * 256 + threadIdx.x;
  if (b >= NPATH) return;
  const float kk = 1.0f + 0.05f * (1.0f / 50.0f);   // 1 + R*DT
  float y = Y0[0];
  const float* cb = cbuf + (long)b * NSTEP;
  #pragma unroll 10
  for (int i = 0; i < NSTEP; ++i) y = y * kk + cb[i];
  Yout[b] = y;
}

extern "C" void kernel_launch(void* const* d_in, const int* in_sizes, int n_in,
                              void* d_out, int out_size, void* d_ws, size_t ws_size,
                              hipStream_t stream)
{
  const float* dw  = (const float*)d_in[0];
  const float* tg  = (const float*)d_in[1];
  const float* W1  = (const float*)d_in[2];
  const float* b1  = (const float*)d_in[3];
  const float* g1  = (const float*)d_in[4];
  const float* be1 = (const float*)d_in[5];
  const float* W2  = (const float*)d_in[6];
  const float* b2  = (const float*)d_in[7];
  const float* g2  = (const float*)d_in[8];
  const float* be2 = (const float*)d_in[9];
  const float* W3  = (const float*)d_in[10];
  const float* b3  = (const float*)d_in[11];
  const float* g3  = (const float*)d_in[12];
  const float* be3 = (const float*)d_in[13];
  const float* W4  = (const float*)d_in[14];
  const float* b4  = (const float*)d_in[15];
  const float* Y0  = (const float*)d_in[16];
  float* out = (float*)d_out;               // [0,8192): Y ; [8192,8192+819200): S

  char* ws = (char*)d_ws;
  unsigned short* WTS = (unsigned short*)ws;        // 131072 B
  float* PPAR = (float*)(ws + 131072);              // 1536 * 4 B
  float* cbuf = (float*)(ws + 137344);              // 409600 * 4 B
  char* chunk = ws + 1775744;                       // X/E chunk region (16B aligned)

  prep_weights<<<256, 256, 0, stream>>>(W1, W2, W3, W4, WTS);
  prep_params<<<6, 256, 0, stream>>>(b1, g1, be1, b2, g2, be2, b3, g3, be3, b4, PPAR);

  long avail = (long)ws_size - 1775744L;
  long pc = (avail > 0) ? (avail / 25600L) : 0;     // per-path: 12800 (X) + 12800 (E) B
  if (pc > 8192) pc = 8192;
  pc -= pc % 128;                                   // rows multiple of 128
  if (pc < 128) pc = 128;

  for (long p0 = 0; p0 < 8192; p0 += pc){
    long np = 8192 - p0; if (np > pc) np = pc;
    unsigned short* Xc = (unsigned short*)chunk;
    unsigned short* Ec = Xc + np * 50L * XSTR;
    phaseA<<<(int)(np / 4), 256, 0, stream>>>(dw, tg, Xc, Ec, out + 8192, (int)p0);
    long nrows = np * 50L;
    phaseB<<<(int)(nrows / 128), 256, 0, stream>>>(Xc, Ec, WTS, PPAR, cbuf, p0 * 50L);
  }
  phaseC<<<32, 256, 0, stream>>>(cbuf, Y0, out);
}